// Round 1
// baseline (160.700 us; speedup 1.0000x reference)
//
#include <hip/hip_runtime.h>
#include <cstdint>
#include <cstddef>

// Problem constants (from reference): B=16, S=2048, E=128, H=768, C=457
constexpr int Bn = 16, Sn = 2048, En = 128, Hn = 768, Cn = 457;
constexpr int TE = 8;     // entities per block in kernel 2
constexpr int CP = 460;   // padded logits row length

// ---------------------------------------------------------------------------
// Kernel 1: entity mean-pool via membership compaction. One block per (b,e).
// Skips unmasked entities entirely (their pooled vectors are never consumed).
// ---------------------------------------------------------------------------
__global__ __launch_bounds__(256) void ent_pool_k(
    const float* __restrict__ hidden,        // (B,S,H) f32
    const int* __restrict__ el,              // (B,S,E) int32 0/1
    const int* __restrict__ elen,            // (B,E) int32
    const unsigned char* __restrict__ emask, // (B,E) bool (1 byte)
    float* __restrict__ ent)                 // (B,E,H) f32 ws
{
  const int be = blockIdx.x;
  if (!emask[be]) return;
  const int b = be >> 7;    // / En
  const int e = be & 127;   // % En

  __shared__ unsigned short lst[Sn];
  __shared__ int cnt;
  const int tid = threadIdx.x;
  if (tid == 0) cnt = 0;
  __syncthreads();

  // compact member token indices
  const int* col = el + ((size_t)b * Sn) * En + e;
  for (int s = tid; s < Sn; s += 256) {
    if (col[(size_t)s * En] != 0) {
      int p = atomicAdd(&cnt, 1);
      lst[p] = (unsigned short)s;
    }
  }
  __syncthreads();
  const int n = cnt;

  // gather-sum: 256 threads cover H=768 as 3 floats each (coalesced rows)
  float a0 = 0.f, a1 = 0.f, a2 = 0.f;
  const float* hb = hidden + (size_t)b * Sn * Hn;
  #pragma unroll 4
  for (int i = 0; i < n; ++i) {
    const float* hr = hb + (size_t)lst[i] * Hn;
    a0 += hr[tid];
    a1 += hr[tid + 256];
    a2 += hr[tid + 512];
  }
  const float inv = 1.0f / (float)elen[be];
  float* o = ent + (size_t)be * Hn;
  o[tid]       = a0 * inv;
  o[tid + 256] = a1 * inv;
  o[tid + 512] = a2 * inv;
}

// ---------------------------------------------------------------------------
// Kernel 2: logits (dot with W rows + bias) and per-entity CE (logsumexp).
// One block per TE=8 entities; eh tile transposed in LDS (broadcast reads).
// Each thread owns 2 consecutive W rows (c = 2*tid, 2*tid+1).
// ---------------------------------------------------------------------------
__global__ __launch_bounds__(256) void logits_ce_k(
    const float* __restrict__ ent,           // (B,E,H)
    const float* __restrict__ Wm,            // (C,H)
    const float* __restrict__ bv,            // (C)
    const int* __restrict__ attr,            // (B,E)
    const unsigned char* __restrict__ emask, // (B,E)
    float* __restrict__ nll)                 // (B*E) masked nll (0 if unmasked)
{
  const int be0 = blockIdx.x * TE;
  const int tid = threadIdx.x;
  __shared__ float eh[Hn][TE];   // 24 KB, transposed: eh[k][e]
  __shared__ float lg[TE][CP];   // ~14.7 KB logits

  unsigned any = 0;
  unsigned char mloc[TE];
  #pragma unroll
  for (int e = 0; e < TE; ++e) { mloc[e] = emask[be0 + e]; any |= mloc[e]; }
  if (!any) {                    // whole tile unmasked: write zeros, done
    if (tid < TE) nll[be0 + tid] = 0.f;
    return;
  }

  // load eh tile (zeros for unmasked entities — their ws rows are garbage)
  #pragma unroll
  for (int e = 0; e < TE; ++e) {
    const float* src = ent + (size_t)(be0 + e) * Hn;
    for (int h = tid; h < Hn; h += 256)
      eh[h][e] = mloc[e] ? src[h] : 0.f;
  }
  __syncthreads();

  const int c0 = tid * 2, c1 = c0 + 1;
  if (c0 < Cn) {
    float acc0[TE], acc1[TE];
    #pragma unroll
    for (int e = 0; e < TE; ++e) { acc0[e] = 0.f; acc1[e] = 0.f; }
    const float* w0 = Wm + (size_t)c0 * Hn;
    const float* w1 = Wm + (size_t)((c1 < Cn) ? c1 : c0) * Hn;
    for (int k = 0; k < Hn; k += 4) {
      const float4 wa = *reinterpret_cast<const float4*>(w0 + k);
      const float4 wb = *reinterpret_cast<const float4*>(w1 + k);
      #pragma unroll
      for (int kk = 0; kk < 4; ++kk) {
        const float4 ea = *reinterpret_cast<const float4*>(&eh[k + kk][0]);
        const float4 eb = *reinterpret_cast<const float4*>(&eh[k + kk][4]);
        const float wva = (&wa.x)[kk], wvb = (&wb.x)[kk];
        acc0[0] += wva * ea.x; acc0[1] += wva * ea.y;
        acc0[2] += wva * ea.z; acc0[3] += wva * ea.w;
        acc0[4] += wva * eb.x; acc0[5] += wva * eb.y;
        acc0[6] += wva * eb.z; acc0[7] += wva * eb.w;
        acc1[0] += wvb * ea.x; acc1[1] += wvb * ea.y;
        acc1[2] += wvb * ea.z; acc1[3] += wvb * ea.w;
        acc1[4] += wvb * eb.x; acc1[5] += wvb * eb.y;
        acc1[6] += wvb * eb.z; acc1[7] += wvb * eb.w;
      }
    }
    const float bb0 = bv[c0];
    #pragma unroll
    for (int e = 0; e < TE; ++e) lg[e][c0] = acc0[e] + bb0;
    if (c1 < Cn) {
      const float bb1 = bv[c1];
      #pragma unroll
      for (int e = 0; e < TE; ++e) lg[e][c1] = acc1[e] + bb1;
    }
  }
  __syncthreads();

  // per-entity logsumexp + nll; 4 waves x 2 entities each
  const int wave = tid >> 6, lane = tid & 63;
  #pragma unroll
  for (int j = 0; j < 2; ++j) {
    const int e = wave * 2 + j;
    float mx = -3.4e38f;
    for (int i = lane; i < Cn; i += 64) mx = fmaxf(mx, lg[e][i]);
    #pragma unroll
    for (int o = 32; o; o >>= 1) mx = fmaxf(mx, __shfl_xor(mx, o, 64));
    float sm = 0.f;
    for (int i = lane; i < Cn; i += 64) sm += __expf(lg[e][i] - mx);
    #pragma unroll
    for (int o = 32; o; o >>= 1) sm += __shfl_xor(sm, o, 64);
    if (lane == 0) {
      const int be = be0 + e;
      float r = 0.f;
      if (emask[be]) {
        const int tg = attr[be];
        r = mx + logf(sm) - lg[e][tg];
      }
      nll[be] = r;
    }
  }
}

// ---------------------------------------------------------------------------
// Kernel 3: deterministic final reduction (2048 values, one block).
// ---------------------------------------------------------------------------
__global__ __launch_bounds__(256) void reduce_k(
    const float* __restrict__ nll,
    const unsigned char* __restrict__ emask,
    float* __restrict__ out)
{
  const int tid = threadIdx.x;
  float s = 0.f, c = 0.f;
  for (int i = tid; i < Bn * En; i += 256) {
    s += nll[i];
    c += (float)emask[i];
  }
  #pragma unroll
  for (int o = 32; o; o >>= 1) {
    s += __shfl_xor(s, o, 64);
    c += __shfl_xor(c, o, 64);
  }
  __shared__ float ws_[4], wc_[4];
  const int wave = tid >> 6, lane = tid & 63;
  if (lane == 0) { ws_[wave] = s; wc_[wave] = c; }
  __syncthreads();
  if (tid == 0) {
    const float S2 = ws_[0] + ws_[1] + ws_[2] + ws_[3];
    const float C2 = wc_[0] + wc_[1] + wc_[2] + wc_[3];
    out[0] = S2 / C2;
  }
}

// ---------------------------------------------------------------------------
extern "C" void kernel_launch(void* const* d_in, const int* in_sizes, int n_in,
                              void* d_out, int out_size, void* d_ws, size_t ws_size,
                              hipStream_t stream) {
  const float* hidden        = (const float*)d_in[0];
  // d_in[1] field_labels, d_in[2] label_masks: unused by the reference loss
  const int* attr            = (const int*)d_in[3];
  const int* el              = (const int*)d_in[4];
  const int* elen            = (const int*)d_in[5];
  const unsigned char* emask = (const unsigned char*)d_in[6]; // jnp bool = 1B
  const float* Wm            = (const float*)d_in[7];
  const float* bv            = (const float*)d_in[8];

  float* ent = (float*)d_ws;                       // B*E*H f32 = 6.29 MB
  float* nll = ent + (size_t)Bn * En * Hn;         // B*E f32

  hipLaunchKernelGGL(ent_pool_k, dim3(Bn * En), dim3(256), 0, stream,
                     hidden, el, elen, emask, ent);
  hipLaunchKernelGGL(logits_ce_k, dim3(Bn * En / TE), dim3(256), 0, stream,
                     ent, Wm, bv, attr, emask, nll);
  hipLaunchKernelGGL(reduce_k, dim3(1), dim3(256), 0, stream,
                     nll, emask, (float*)d_out);
}

// Round 3
// 85.538 us; speedup vs baseline: 1.8787x; 1.8787x over previous
//
#include <hip/hip_runtime.h>
#include <hip/hip_bf16.h>
#include <cstdint>
#include <cstddef>

// Problem constants: B=16, S=2048, E=128, H=768, C=457
constexpr int Bn = 16, Sn = 2048, En = 128, Hn = 768, Cn = 457;
constexpr int NP = 512;                 // padded class dim for GEMM
using f32x4  = __attribute__((ext_vector_type(4))) float;
using bf16x8 = __attribute__((ext_vector_type(8))) short;

static __device__ inline unsigned short f2bf(float x) {
  __hip_bfloat16 b = __float2bfloat16(x);
  return *reinterpret_cast<unsigned short*>(&b);
}

// ---------------------------------------------------------------------------
// Kernel 1: entity mean-pool via membership compaction. One block per (b,e).
// Skips unmasked entities. Output written as bf16 (GEMM A operand).
// ---------------------------------------------------------------------------
__global__ __launch_bounds__(256) void ent_pool_k(
    const float* __restrict__ hidden,        // (B,S,H) f32
    const int* __restrict__ el,              // (B,S,E) int32 0/1
    const int* __restrict__ elen,            // (B,E) int32
    const unsigned char* __restrict__ emask, // (B,E) bool
    unsigned short* __restrict__ entbf)      // (B*E, H) bf16 ws
{
  const int be = blockIdx.x;
  if (!emask[be]) return;
  const int b = be >> 7;

  __shared__ unsigned short lst[Sn];
  __shared__ int cnt;
  const int tid = threadIdx.x;
  if (tid == 0) cnt = 0;
  __syncthreads();

  const int* col = el + ((size_t)b * Sn) * En + (be & 127);
  for (int s = tid; s < Sn; s += 256) {
    if (col[(size_t)s * En] != 0) {
      int p = atomicAdd(&cnt, 1);
      lst[p] = (unsigned short)s;
    }
  }
  __syncthreads();
  const int n = cnt;

  float a0 = 0.f, a1 = 0.f, a2 = 0.f;
  const float* hb = hidden + (size_t)b * Sn * Hn;
  #pragma unroll 4
  for (int i = 0; i < n; ++i) {
    const float* hr = hb + (size_t)lst[i] * Hn;
    a0 += hr[tid];
    a1 += hr[tid + 256];
    a2 += hr[tid + 512];
  }
  const float inv = 1.0f / (float)elen[be];
  unsigned short* o = entbf + (size_t)be * Hn;
  o[tid]       = f2bf(a0 * inv);
  o[tid + 256] = f2bf(a1 * inv);
  o[tid + 512] = f2bf(a2 * inv);
}

// ---------------------------------------------------------------------------
// Kernel 2: cast W (457,768) f32 -> (512,768) bf16, zero-padding rows >= 457.
// ---------------------------------------------------------------------------
__global__ __launch_bounds__(256) void cast_w_k(
    const float* __restrict__ Wm, unsigned short* __restrict__ wbf)
{
  const int c = blockIdx.x;          // 0..511
  const int tid = threadIdx.x;
  unsigned short* dst = wbf + (size_t)c * Hn;
  if (c < Cn) {
    const float* src = Wm + (size_t)c * Hn;
    #pragma unroll
    for (int j = 0; j < 3; ++j) dst[tid + j * 256] = f2bf(src[tid + j * 256]);
  } else {
    #pragma unroll
    for (int j = 0; j < 3; ++j) dst[tid + j * 256] = 0;
  }
}

// ---------------------------------------------------------------------------
// Kernel 3: logits GEMM. C[2048][512] = A[2048][768] * B^T[512][768], bf16
// MFMA 16x16x32, fp32 accum. Tile 128x64, 4 waves (2x2), BK=32.
// ---------------------------------------------------------------------------
constexpr int BM = 128, BN = 64, BK = 32, LDP = BK + 24;   // 112B row stride
__global__ __launch_bounds__(256) void gemm_k(
    const unsigned short* __restrict__ A,   // (2048,768) bf16
    const unsigned short* __restrict__ Bm,  // (512,768) bf16 (B^T layout)
    float* __restrict__ Cm)                 // (2048,512) f32
{
  __shared__ unsigned short As[BM][LDP];
  __shared__ unsigned short Bs[BN][LDP];
  const int bm = blockIdx.x, bn = blockIdx.y;
  const int tid = threadIdx.x, lane = tid & 63, wv = tid >> 6;
  const int wm = wv >> 1, wn = wv & 1;          // 2x2 wave grid

  f32x4 acc[4][2] = {};

  for (int k0 = 0; k0 < Hn; k0 += BK) {
    // stage A tile: 128 rows x 32 elems = 512 chunks of 8 bf16; 2 per thread
    #pragma unroll
    for (int i = 0; i < 2; ++i) {
      const int idx = tid + i * 256;
      const int r = idx >> 2, kc = (idx & 3) * 8;
      const unsigned short* src = A + (size_t)(bm * BM + r) * Hn + k0 + kc;
      *reinterpret_cast<ulonglong2*>(&As[r][kc]) =
          *reinterpret_cast<const ulonglong2*>(src);
    }
    // stage B tile: 64 rows x 32 elems = 256 chunks; 1 per thread
    {
      const int r = tid >> 2, kc = (tid & 3) * 8;
      const unsigned short* src = Bm + (size_t)(bn * BN + r) * Hn + k0 + kc;
      *reinterpret_cast<ulonglong2*>(&Bs[r][kc]) =
          *reinterpret_cast<const ulonglong2*>(src);
    }
    __syncthreads();

    const int kr = (lane >> 4) * 8, rl = lane & 15;
    bf16x8 af[4], bf[2];
    #pragma unroll
    for (int mi = 0; mi < 4; ++mi)
      af[mi] = *reinterpret_cast<const bf16x8*>(&As[wm * 64 + mi * 16 + rl][kr]);
    #pragma unroll
    for (int ni = 0; ni < 2; ++ni)
      bf[ni] = *reinterpret_cast<const bf16x8*>(&Bs[wn * 32 + ni * 16 + rl][kr]);
    #pragma unroll
    for (int mi = 0; mi < 4; ++mi)
      #pragma unroll
      for (int ni = 0; ni < 2; ++ni)
        acc[mi][ni] = __builtin_amdgcn_mfma_f32_16x16x32_bf16(
            af[mi], bf[ni], acc[mi][ni], 0, 0, 0);
    __syncthreads();
  }

  // epilogue: col = lane&15, row = (lane>>4)*4 + r  (m89-verified C/D layout)
  const int cl = lane & 15, rg = (lane >> 4) * 4;
  #pragma unroll
  for (int mi = 0; mi < 4; ++mi)
    #pragma unroll
    for (int ni = 0; ni < 2; ++ni) {
      const int col = bn * BN + wn * 32 + ni * 16 + cl;
      #pragma unroll
      for (int r = 0; r < 4; ++r) {
        const int row = bm * BM + wm * 64 + mi * 16 + rg + r;
        Cm[(size_t)row * NP + col] = acc[mi][ni][r];
      }
    }
}

// ---------------------------------------------------------------------------
// Kernel 4: CE per entity (one wave each; 4 waves/block). Bias added here.
// ---------------------------------------------------------------------------
__global__ __launch_bounds__(256) void ce_k(
    const float* __restrict__ logits,        // (2048,512)
    const float* __restrict__ bv,            // (457)
    const int* __restrict__ attr,            // (B,E)
    const unsigned char* __restrict__ emask, // (B,E)
    float* __restrict__ nll)                 // (2048)
{
  const int wv = threadIdx.x >> 6, lane = threadIdx.x & 63;
  const int be = blockIdx.x * 4 + wv;
  if (!emask[be]) { if (lane == 0) nll[be] = 0.f; return; }
  const float* row = logits + (size_t)be * NP;

  float mx = -3.4e38f;
  for (int i = lane; i < Cn; i += 64) mx = fmaxf(mx, row[i] + bv[i]);
  #pragma unroll
  for (int o = 32; o; o >>= 1) mx = fmaxf(mx, __shfl_xor(mx, o, 64));
  float sm = 0.f;
  for (int i = lane; i < Cn; i += 64) sm += __expf(row[i] + bv[i] - mx);
  #pragma unroll
  for (int o = 32; o; o >>= 1) sm += __shfl_xor(sm, o, 64);
  if (lane == 0) {
    const int tg = attr[be];
    nll[be] = mx + logf(sm) - (row[tg] + bv[tg]);
  }
}

// ---------------------------------------------------------------------------
// Kernel 5: deterministic final reduction.
// ---------------------------------------------------------------------------
__global__ __launch_bounds__(256) void reduce_k(
    const float* __restrict__ nll,
    const unsigned char* __restrict__ emask,
    float* __restrict__ out)
{
  const int tid = threadIdx.x;
  float s = 0.f, c = 0.f;
  for (int i = tid; i < Bn * En; i += 256) {
    s += nll[i];
    c += (float)emask[i];
  }
  #pragma unroll
  for (int o = 32; o; o >>= 1) {
    s += __shfl_xor(s, o, 64);
    c += __shfl_xor(c, o, 64);
  }
  __shared__ float ws_[4], wc_[4];
  const int wave = tid >> 6, lane = tid & 63;
  if (lane == 0) { ws_[wave] = s; wc_[wave] = c; }
  __syncthreads();
  if (tid == 0) {
    out[0] = (ws_[0] + ws_[1] + ws_[2] + ws_[3]) /
             (wc_[0] + wc_[1] + wc_[2] + wc_[3]);
  }
}

// ---------------------------------------------------------------------------
extern "C" void kernel_launch(void* const* d_in, const int* in_sizes, int n_in,
                              void* d_out, int out_size, void* d_ws, size_t ws_size,
                              hipStream_t stream) {
  const float* hidden        = (const float*)d_in[0];
  const int* attr            = (const int*)d_in[3];
  const int* el              = (const int*)d_in[4];
  const int* elen            = (const int*)d_in[5];
  const unsigned char* emask = (const unsigned char*)d_in[6];
  const float* Wm            = (const float*)d_in[7];
  const float* bv            = (const float*)d_in[8];

  unsigned short* entbf = (unsigned short*)d_ws;            // 2048*768 bf16
  unsigned short* wbf   = entbf + (size_t)Bn * En * Hn;     // 512*768 bf16
  float* logits = (float*)(wbf + (size_t)NP * Hn);          // 2048*512 f32
  float* nll    = logits + (size_t)Bn * En * NP;            // 2048 f32

  hipLaunchKernelGGL(ent_pool_k, dim3(Bn * En), dim3(256), 0, stream,
                     hidden, el, elen, emask, entbf);
  hipLaunchKernelGGL(cast_w_k, dim3(NP), dim3(256), 0, stream, Wm, wbf);
  hipLaunchKernelGGL(gemm_k, dim3(Bn * En / BM, NP / BN), dim3(256), 0, stream,
                     entbf, wbf, logits);
  hipLaunchKernelGGL(ce_k, dim3(Bn * En / 4), dim3(256), 0, stream,
                     logits, bv, attr, emask, nll);
  hipLaunchKernelGGL(reduce_k, dim3(1), dim3(256), 0, stream,
                     nll, emask, (float*)d_out);
}